// Round 7
// baseline (499.355 us; speedup 1.0000x reference)
//
#include <hip/hip_runtime.h>
#include <stdint.h>

// Problem constants
#define N_E    1024
#define E_DIM  512
#define BATCH  16
#define HW     4096                       // 64*64
#define NROW   (BATCH * HW)               // 65536 vectors
#define ZQ_SIZE (BATCH * E_DIM * HW)
#define LOSS_OFF ZQ_SIZE
#define IDX_OFF (ZQ_SIZE + 1)

typedef _Float16 half_t;
typedef __attribute__((ext_vector_type(2)))  __fp16   fp16x2;  // cvt_pkrtz native type
typedef __attribute__((ext_vector_type(8)))  _Float16 frag8;   // 4 VGPR MFMA operand
typedef __attribute__((ext_vector_type(16))) float    accv;    // 16 AGPR accumulator

union U32H2 { fp16x2 h; uint32_t u; };

static __device__ inline uint32_t pack2(float a, float b) {
    U32H2 t; t.h = __builtin_amdgcn_cvt_pkrtz(a, b); return t.u;
}

// Async global->LDS DMA, 16B per lane. LDS dest = wave-uniform base + lane*16.
static __device__ __forceinline__ void dma16(const void* g, void* l) {
    __builtin_amdgcn_global_load_lds(
        (const __attribute__((address_space(1))) void*)g,
        (__attribute__((address_space(3))) void*)l,
        16, 0, 0);
}

// ---------------------------------------------------------------------------
// Tile image format (verified on HW, rounds 4/6): one tile = R rows x 32 k,
// row = 128 B = 8 slots of 16 B. Logical slot s (0..3 = hi-f16, k=s*8..s*8+7;
// 4..7 = lo-f16), dword d holds elements 2d,2d+1 as (f16(k+1)<<16 | f16(k)).
// Physical slot = logical ^ (row & 7): frag ds_read_b128 (32 consecutive rows,
// fixed logical slot) hits 8 distinct slots per 8-lane group (conflict floor),
// and global_load_lds can stage the tile linearly.
//
// cbP tile ORDER is ks-major: tile index t = ks*8 + jt (== argmin phase index).
// ---------------------------------------------------------------------------
// Kernel 1: codebook prep.
//   blocks [0,128)   : pack one (ks,jt) codebook tile -> cbP (lives in d_out!)
//   blocks [128,640) : codebook transpose (ct) + code norms (cn)
__global__ void k_pack(const float* __restrict__ cb,
                       uint32_t* __restrict__ cbP,
                       float* __restrict__ cn,
                       float* __restrict__ ct) {
    __shared__ float tsh[32][33];
    int bidx = blockIdx.x;
    int tid  = threadIdx.x;

    if (bidx < 128) {
        // ---- codebook pack: tile index bidx = ks*8 + jt (ks-major!) ----
        int jt = bidx & 7, ks = bidx >> 3;
        int kq = tid & 7, jb = tid >> 3;
        uint32_t* tile = cbP + (size_t)bidx * 4096;
        int sH = kq >> 1, o = (kq & 1) * 2;
        #pragma unroll
        for (int r = 0; r < 4; r++) {
            int j = jb + 32 * r;
            float4 v = *(const float4*)(cb + (size_t)(jt * 128 + j) * E_DIM + ks * 32 + kq * 4);
            uint32_t H01 = pack2(v.x, v.y);
            uint32_t H23 = pack2(v.z, v.w);
            U32H2 h01; h01.u = H01; U32H2 h23; h23.u = H23;
            uint32_t L01 = pack2(v.x - (float)h01.h.x, v.y - (float)h01.h.y);
            uint32_t L23 = pack2(v.z - (float)h23.h.x, v.w - (float)h23.h.y);
            int dH = ((sH)     ^ (j & 7)) * 4 + o;
            int dL = ((sH + 4) ^ (j & 7)) * 4 + o;
            *(uint2*)(tile + j * 32 + dH) = make_uint2(H01, H23);
            *(uint2*)(tile + j * 32 + dL) = make_uint2(L01, L23);
        }
    } else {
        // ---- ct transpose (512 blocks) + cn norms (first 256) ----
        int pb = bidx - 128;
        int tx = tid & 31, ty = tid >> 5;
        int jtp = pb & 31, ctl = pb >> 5;
        int j0 = jtp * 32, c0 = ctl * 32;
        #pragma unroll
        for (int i = 0; i < 4; i++) {
            int row = ty + i * 8;
            tsh[row][tx] = cb[(size_t)(j0 + row) * E_DIM + c0 + tx];
        }
        __syncthreads();
        #pragma unroll
        for (int i = 0; i < 4; i++) {
            int row = ty + i * 8;
            ct[(size_t)(c0 + row) * N_E + j0 + tx] = tsh[tx][row];
        }
        if (pb < 256) {
            int lane = tid & 63;
            int wvid = tid >> 6;
            int j = pb * 4 + wvid;
            const float* rowp = cb + (size_t)j * E_DIM;
            float s = 0.f;
            #pragma unroll
            for (int k = 0; k < E_DIM; k += 64) {
                float v = rowp[k + lane];
                s += v * v;
            }
            #pragma unroll
            for (int m = 32; m >= 1; m >>= 1) s += __shfl_xor(s, m);
            if (lane == 0) cn[j] = s;
        }
    }
}

// ---------------------------------------------------------------------------
// Kernel 2: MFMA distance argmin. Grid 1024 (1 block/CU, 8 waves), 64 rows.
// Identical protocol to the verified round-6 kernel, but the B frag ds_reads
// are REGISTER-PIPELINED one phase ahead: iteration p issues the reads for
// tile p+1 (already landed, per vmcnt(2)) and runs phase p's 6 MFMAs from
// registers loaded last iteration -- the LDS-read time (~430 cyc/CU/phase)
// now overlaps the MFMA time (~380) instead of serializing with it.
// Buffer/vmcnt ledger unchanged: outstanding at iter top = tiles {p+1,p+2};
// vmcnt(2) -> p+1 landed; BSTAGE(p+3) after lgkmcnt(0)+barrier. Tail: no
// stage at p=125/126, vmcnt(0) at p=126, MFMA-only at p=127.
// A frags are read in-phase at jt==0 (compiler emits lgkmcnt(4): only the
// first MFMA of that phase waits on them). Reg budget: ~124 VGPR + 128 AGPR
// = 252 <= 256 for 2 waves/SIMD (no spill -- round-4 lesson).
__global__ __launch_bounds__(512, 2) void k_argmin_mfma(
        const float* __restrict__ z,
        const uint32_t* __restrict__ cbP,
        const float* __restrict__ cn,
        uint32_t* __restrict__ bestIdx) {
    // A image: dwords [0, 32768) = 16 chunks * 2048; B: [32768, 40960), 2 bufs
    __shared__ uint32_t lds[40960];   // 160 KiB exactly

    int tid  = threadIdx.x;
    int lane = tid & 63;
    int l31  = lane & 31;
    int lh   = lane >> 5;
    int wid  = tid >> 6;         // wave 0..7
    int wm   = wid & 1;          // row half (32 rows)
    int wg   = wid >> 1;         // code quarter (32 codes of the 128-tile)

    int n0 = blockIdx.x * 64;
    int b  = n0 >> 12, hw0 = n0 & 4095;

    // ---- prologue: pack A (64 rows x 512 ch) into LDS, read z ONCE ----
    {
        int r  = tid & 63;       // row (lane-consecutive -> coalesced loads)
        int kg = tid >> 6;       // 64-channel group
        const float* zB = z + (size_t)b * E_DIM * HW + hw0 + r;
        #pragma unroll
        for (int g = 0; g < 16; g++) {
            int ch0 = kg * 64 + g * 4;
            float v0 = zB[(size_t)(ch0    ) * HW];
            float v1 = zB[(size_t)(ch0 + 1) * HW];
            float v2 = zB[(size_t)(ch0 + 2) * HW];
            float v3 = zB[(size_t)(ch0 + 3) * HW];
            uint32_t H01 = pack2(v0, v1);
            uint32_t H23 = pack2(v2, v3);
            U32H2 h01; h01.u = H01; U32H2 h23; h23.u = H23;
            uint32_t L01 = pack2(v0 - (float)h01.h.x, v1 - (float)h01.h.y);
            uint32_t L23 = pack2(v2 - (float)h23.h.x, v3 - (float)h23.h.y);
            int chunk = ch0 >> 5;
            int kq = (ch0 & 31) >> 2;
            uint32_t* base = lds + chunk * 2048 + r * 32;
            int o = (kq & 1) * 2, sH = kq >> 1, sw = r & 7;
            *(uint2*)&base[(((sH    ) ^ sw) << 2) + o] = make_uint2(H01, H23);
            *(uint2*)&base[(((sH + 4) ^ sw) << 2) + o] = make_uint2(L01, L23);
        }
    }
    __syncthreads();   // A image complete; vmcnt drained to 0 (counted base)

    accv acc[8];
    #pragma unroll
    for (int j = 0; j < 8; j++)
        #pragma unroll
        for (int i = 0; i < 16; i++) acc[j][i] = 0.f;

    int uoffB = wid * 2048;      // wave's 2 KiB slice of a 16 KiB B tile
    // stage B tile q (= phase q, ks-major order) into buf[q&1]
    #define BSTAGE(q) do {                                                     \
        char* lb_ = (char*)(lds + 32768) + ((q) & 1) * 16384 + uoffB;          \
        const char* gb_ = (const char*)cbP + (size_t)(q) * 16384               \
                          + uoffB + lane * 16;                                 \
        dma16(gb_,        lb_);                                                \
        dma16(gb_ + 1024, lb_ + 1024);                                         \
    } while (0)

    int arow = wm * 32 + l31, asw = arow & 7;
    int nn   = wg * 32 + l31, nsw = nn & 7;

    frag8 aH0, aL0, aH1, aL1;            // A frags for the CURRENT ks
    frag8 bH0, bL0, bH1, bL1;            // B frags for the CURRENT phase
    frag8 nH0, nL0, nH1, nL1;            // B frags being prefetched (next)

    // ---- pipeline prologue: stage tiles 0,1; preload frags(0) ----
    BSTAGE(0);
    BSTAGE(1);
    asm volatile("s_waitcnt vmcnt(2)" ::: "memory");   // tile 0 landed
    __builtin_amdgcn_s_barrier();
    {
        const uint32_t* Bb = lds + 32768 + nn * 32;    // buf0
        bH0 = *(const frag8*)&Bb[(((    lh) ^ nsw) << 2)];
        bL0 = *(const frag8*)&Bb[(((4 + lh) ^ nsw) << 2)];
        bH1 = *(const frag8*)&Bb[(((2 + lh) ^ nsw) << 2)];
        bL1 = *(const frag8*)&Bb[(((6 + lh) ^ nsw) << 2)];
    }
    asm volatile("s_waitcnt lgkmcnt(0)" ::: "memory"); // all waves read buf0
    __builtin_amdgcn_s_barrier();
    BSTAGE(2);                                         // overwrites buf0: safe

    // Iteration = phase p (MFMA(p) from regs) + prefetch of tile p+1.
    //   jt_:     compile-time phase-within-ks (acc index, buffer parity)
    //   vm_:     vmcnt literal ("2" steady / "0" at p=126)
    //   stage_:  issue BSTAGE(pb+jt_+3)?
    //   load_:   prefetch tile p+1? (false only at p=127)
    //   ksA_:    A chunk to read when jt_==0
    #define PH(jt_, vm_, stage_, load_, ksA_, pb_) do {                        \
        if (load_) {                                                           \
            asm volatile("s_waitcnt vmcnt(" vm_ ")" ::: "memory");             \
            __builtin_amdgcn_s_barrier();                                      \
            if ((jt_) == 0) {                                                  \
                const uint32_t* Ac_ = lds + (ksA_) * 2048 + arow * 32;         \
                aH0 = *(const frag8*)&Ac_[(((    lh) ^ asw) << 2)];            \
                aL0 = *(const frag8*)&Ac_[(((4 + lh) ^ asw) << 2)];            \
                aH1 = *(const frag8*)&Ac_[(((2 + lh) ^ asw) << 2)];            \
                aL1 = *(const frag8*)&Ac_[(((6 + lh) ^ asw) << 2)];            \
            }                                                                  \
            const uint32_t* Bb_ = lds + 32768                                  \
                                  + (((jt_) + 1) & 1) * 4096 + nn * 32;        \
            nH0 = *(const frag8*)&Bb_[(((    lh) ^ nsw) << 2)];                \
            nL0 = *(const frag8*)&Bb_[(((4 + lh) ^ nsw) << 2)];                \
            nH1 = *(const frag8*)&Bb_[(((2 + lh) ^ nsw) << 2)];                \
            nL1 = *(const frag8*)&Bb_[(((6 + lh) ^ nsw) << 2)];                \
        }                                                                      \
        __builtin_amdgcn_s_setprio(1);                                         \
        acc[jt_] = __builtin_amdgcn_mfma_f32_32x32x16_f16(aH0, bH0, acc[jt_], 0, 0, 0); \
        acc[jt_] = __builtin_amdgcn_mfma_f32_32x32x16_f16(aH0, bL0, acc[jt_], 0, 0, 0); \
        acc[jt_] = __builtin_amdgcn_mfma_f32_32x32x16_f16(aL0, bH0, acc[jt_], 0, 0, 0); \
        acc[jt_] = __builtin_amdgcn_mfma_f32_32x32x16_f16(aH1, bH1, acc[jt_], 0, 0, 0); \
        acc[jt_] = __builtin_amdgcn_mfma_f32_32x32x16_f16(aH1, bL1, acc[jt_], 0, 0, 0); \
        acc[jt_] = __builtin_amdgcn_mfma_f32_32x32x16_f16(aL1, bH1, acc[jt_], 0, 0, 0); \
        __builtin_amdgcn_s_setprio(0);                                         \
        if (load_) {                                                           \
            asm volatile("s_waitcnt lgkmcnt(0)" ::: "memory");                 \
            __builtin_amdgcn_s_barrier();                                      \
            if (stage_) BSTAGE((pb_) + (jt_) + 3);                             \
            bH0 = nH0; bL0 = nL0; bH1 = nH1; bL1 = nL1;                        \
        }                                                                      \
    } while (0)

    #pragma unroll 1
    for (int ks = 0; ks < 15; ks++) {
        int pb = ks * 8;
        PH(0, "2", true, true, ks, pb);
        PH(1, "2", true, true, 0,  pb);
        PH(2, "2", true, true, 0,  pb);
        PH(3, "2", true, true, 0,  pb);
        PH(4, "2", true, true, 0,  pb);
        PH(5, "2", true, true, 0,  pb);
        PH(6, "2", true, true, 0,  pb);
        PH(7, "2", true, true, 0,  pb);
    }
    {   // ks = 15 tail: phases 120..127
        PH(0, "2", true,  true,  15, 120);   // p=120, stage 123
        PH(1, "2", true,  true,  0,  120);   // p=121, stage 124
        PH(2, "2", true,  true,  0,  120);   // p=122, stage 125
        PH(3, "2", true,  true,  0,  120);   // p=123, stage 126
        PH(4, "2", true,  true,  0,  120);   // p=124, stage 127 (last tile)
        PH(5, "2", false, true,  0,  120);   // p=125, load 126, no stage
        PH(6, "0", false, true,  0,  120);   // p=126, load 127 (vmcnt 0)
        PH(7, "0", false, false, 0,  120);   // p=127, MFMA only
    }
    #undef PH
    #undef BSTAGE

    // ---- final fold: per-lane argmin over jt, 32-lane butterfly (codes),
    // then cross-wg combine via LDS packed-u64 keys (round-3 fix) ----
    float cnl[8];
    #pragma unroll
    for (int j = 0; j < 8; j++) cnl[j] = cn[j * 128 + wg * 32 + l31];

    unsigned long long* red = (unsigned long long*)(lds + 32768);
    #pragma unroll
    for (int r = 0; r < 16; r++) {
        float v = 1e30f; int ix = 0;
        #pragma unroll
        for (int j = 0; j < 8; j++) {
            float d = cnl[j] - 2.f * acc[j][r];
            int code = j * 128 + wg * 32 + l31;
            if (d < v) { v = d; ix = code; }   // ascending j keeps lowest idx on ties
        }
        #pragma unroll
        for (int m = 1; m <= 16; m <<= 1) {
            float ov = __shfl_xor(v, m);
            int   oi = __shfl_xor(ix, m);
            if (ov < v || (ov == v && oi < ix)) { v = ov; ix = oi; }
        }
        if (l31 == r) {
            int row = wm * 32 + (r & 3) + 8 * (r >> 2) + 4 * lh;
            uint32_t s = __float_as_uint(v);
            uint32_t k32 = (s & 0x80000000u) ? ~s : (s | 0x80000000u);
            red[wg * 64 + row] = ((unsigned long long)k32 << 32) | (uint32_t)ix;
        }
    }
    __syncthreads();
    if (tid < 64) {
        unsigned long long k0 = red[tid];
        unsigned long long k1 = red[64 + tid];
        unsigned long long k2 = red[128 + tid];
        unsigned long long k3 = red[192 + tid];
        unsigned long long k = k0 < k1 ? k0 : k1;
        if (k2 < k) k = k2;
        if (k3 < k) k = k3;
        bestIdx[n0 + tid] = (uint32_t)k;
    }
}

// ---------------------------------------------------------------------------
// Kernel 3: gather z_q, straight-through output, per-block loss partials.
__global__ void k_gather_loss(const float* __restrict__ z,
                              const float* __restrict__ ct,
                              const uint32_t* __restrict__ bestIdx,
                              float* __restrict__ out,
                              float* __restrict__ pl) {
    int g = blockIdx.x * blockDim.x + threadIdx.x;
    int w4 = g & 1023;
    int bc = g >> 10;
    int c  = bc & 511;
    int b  = bc >> 9;
    int n4 = b * 1024 + w4;

    uint4 iv = *(const uint4*)(bestIdx + (size_t)n4 * 4);

    const float* ctc = ct + (size_t)c * N_E;
    float4 zq;
    zq.x = ctc[iv.x]; zq.y = ctc[iv.y]; zq.z = ctc[iv.z]; zq.w = ctc[iv.w];
    float4 zv = *(const float4*)(z + (size_t)g * 4);

    float4 d;
    d.x = zq.x - zv.x; d.y = zq.y - zv.y; d.z = zq.z - zv.z; d.w = zq.w - zv.w;
    float4 o;
    o.x = zv.x + d.x; o.y = zv.y + d.y; o.z = zv.z + d.z; o.w = zv.w + d.w;
    *(float4*)(out + (size_t)g * 4) = o;

    float ls = d.x * d.x + d.y * d.y + d.z * d.z + d.w * d.w;
    #pragma unroll
    for (int m = 32; m >= 1; m >>= 1) ls += __shfl_xor(ls, m);

    __shared__ float wsum[4];
    int lane = threadIdx.x & 63, wvid = threadIdx.x >> 6;
    if (lane == 0) wsum[wvid] = ls;
    __syncthreads();
    if (threadIdx.x == 0)
        pl[blockIdx.x] = wsum[0] + wsum[1] + wsum[2] + wsum[3];

    if (c == 0) {
        float* ip = out + IDX_OFF + (size_t)n4 * 4;
        ip[0] = (float)iv.x; ip[1] = (float)iv.y;
        ip[2] = (float)iv.z; ip[3] = (float)iv.w;
    }
}

// ---------------------------------------------------------------------------
// Kernel 4: reduce 8192 partials -> loss
__global__ void k_final(const float* __restrict__ pl, float* __restrict__ out) {
    float s = 0.f;
    for (int i = threadIdx.x; i < 8192; i += 256) s += pl[i];
    #pragma unroll
    for (int m = 32; m >= 1; m >>= 1) s += __shfl_xor(s, m);
    __shared__ float wsum[4];
    int lane = threadIdx.x & 63, wvid = threadIdx.x >> 6;
    if (lane == 0) wsum[wvid] = s;
    __syncthreads();
    if (threadIdx.x == 0) {
        float tot = wsum[0] + wsum[1] + wsum[2] + wsum[3];
        out[LOSS_OFF] = 1.25f * tot / (float)ZQ_SIZE;
    }
}

// ---------------------------------------------------------------------------
extern "C" void kernel_launch(void* const* d_in, const int* in_sizes, int n_in,
                              void* d_out, int out_size, void* d_ws, size_t ws_size,
                              hipStream_t stream) {
    (void)in_sizes; (void)n_in; (void)out_size; (void)ws_size;
    const float* z  = (const float*)d_in[0];
    const float* cb = (const float*)d_in[1];
    float* out = (float*)d_out;

    // Workspace: 2.39 MiB total (proven available).
    float* cn = (float*)d_ws + 16;                       // 1024 f   (4 KiB)
    float* ct = cn + 1024;                               // 512x1024 f (2 MiB)
    uint32_t* bestIdx = (uint32_t*)(ct + 512 * 1024);    // 65536 u32 (256 KiB)
    float* pl = (float*)(bestIdx + NROW);                // 8192 f   (32 KiB)

    // Pre-packed codebook tiles (2 MiB) live in the FIRST 2 MiB of d_out:
    // written by k_pack, consumed by k_argmin, then overwritten by k_gather.
    uint32_t* cbP = (uint32_t*)d_out;

    k_pack<<<640, 256, 0, stream>>>(cb, cbP, cn, ct);
    k_argmin_mfma<<<1024, 512, 0, stream>>>(z, cbP, cn, bestIdx);
    k_gather_loss<<<ZQ_SIZE / 4 / 256, 256, 0, stream>>>(z, ct, bestIdx, out, pl);
    k_final<<<1, 256, 0, stream>>>(pl, out);
}